// Round 1
// baseline (1018.118 us; speedup 1.0000x reference)
//
#include <hip/hip_runtime.h>
#include <cstddef>

// Problem constants
constexpr int B_ = 4, H_ = 96, W_ = 96, C_ = 192, QKVC = 576;
constexpr int NPIX = B_ * H_ * W_;           // 36864
constexpr float SCALE = 0.17677669529663689f; // 32^-0.5

// ---------------------------------------------------------------------------
// Tiled fp32 GEMM: C[M,N] = A[M,K] @ B[K,N] + bias[N]
// BM=BN=BK=64, 256 threads, 4x4 microtile per thread.
// M % 64 == 0, N % 64 == 0, K % 64 == 0 (holds: 36864, 576/192, 192).
// ---------------------------------------------------------------------------
__global__ __launch_bounds__(256) void gemm_bias_kernel(
    const float* __restrict__ A, const float* __restrict__ B,
    const float* __restrict__ bias, float* __restrict__ C,
    int M, int N, int K)
{
    __shared__ float As[64][68];   // [m][k], +4 pad breaks stride-64 bank conflicts
    __shared__ float Bs[64][64];   // [k][n]

    const int tid = threadIdx.x;
    const int tx = tid & 15;       // n direction (16)
    const int ty = tid >> 4;       // m direction (16)
    const int ntiles = N >> 6;
    const int m0 = (blockIdx.x / ntiles) << 6;
    const int n0 = (blockIdx.x % ntiles) << 6;

    float acc[4][4];
    #pragma unroll
    for (int i = 0; i < 4; ++i)
        #pragma unroll
        for (int j = 0; j < 4; ++j) acc[i][j] = 0.f;

    for (int k0 = 0; k0 < K; k0 += 64) {
        // stage A tile (64 rows x 64 k) as float4
        #pragma unroll
        for (int it = 0; it < 4; ++it) {
            int idx = it * 256 + tid;
            int r = idx >> 4;
            int c4 = (idx & 15) << 2;
            float4 va = *(const float4*)(A + (size_t)(m0 + r) * K + k0 + c4);
            *(float4*)(&As[r][c4]) = va;
        }
        // stage B tile (64 k x 64 n) as float4
        #pragma unroll
        for (int it = 0; it < 4; ++it) {
            int idx = it * 256 + tid;
            int r = idx >> 4;
            int c4 = (idx & 15) << 2;
            float4 vb = *(const float4*)(B + (size_t)(k0 + r) * N + n0 + c4);
            *(float4*)(&Bs[r][c4]) = vb;
        }
        __syncthreads();

        #pragma unroll 8
        for (int k = 0; k < 64; ++k) {
            float a0 = As[ty * 4 + 0][k];
            float a1 = As[ty * 4 + 1][k];
            float a2 = As[ty * 4 + 2][k];
            float a3 = As[ty * 4 + 3][k];
            float4 b4 = *(const float4*)(&Bs[k][tx * 4]);
            acc[0][0] += a0 * b4.x; acc[0][1] += a0 * b4.y; acc[0][2] += a0 * b4.z; acc[0][3] += a0 * b4.w;
            acc[1][0] += a1 * b4.x; acc[1][1] += a1 * b4.y; acc[1][2] += a1 * b4.z; acc[1][3] += a1 * b4.w;
            acc[2][0] += a2 * b4.x; acc[2][1] += a2 * b4.y; acc[2][2] += a2 * b4.z; acc[2][3] += a2 * b4.w;
            acc[3][0] += a3 * b4.x; acc[3][1] += a3 * b4.y; acc[3][2] += a3 * b4.z; acc[3][3] += a3 * b4.w;
        }
        __syncthreads();
    }

    float4 bb = *(const float4*)(bias + n0 + tx * 4);
    #pragma unroll
    for (int i = 0; i < 4; ++i) {
        float4 o;
        o.x = acc[i][0] + bb.x;
        o.y = acc[i][1] + bb.y;
        o.z = acc[i][2] + bb.z;
        o.w = acc[i][3] + bb.w;
        *(float4*)(C + (size_t)(m0 + ty * 4 + i) * N + n0 + tx * 4) = o;
    }
}

// ---------------------------------------------------------------------------
// Neighborhood attention: one thread per (pixel, head, kernel-group).
// qkv layout: [pix][576], group g channels at g*192 + {q:0, k:64, v:128} + h*32.
// Output: attn[pix][192], channel = g*64 + h*32 + d.
// Softmax computed without max-subtraction (scores ~N(0,0.08), exp safe).
// ---------------------------------------------------------------------------
__global__ __launch_bounds__(256) void na2d_kernel(
    const float* __restrict__ qkv, float* __restrict__ out)
{
    const int gh  = blockIdx.x / 144;                    // 0..5, uniform per block
    const int pix = (blockIdx.x % 144) * 256 + threadIdx.x; // 0..36863
    const int g = gh >> 1;
    const int h = gh & 1;
    const int K = 7 + 2 * g;                             // 7, 9, 11

    const int b  = pix / (H_ * W_);
    const int ij = pix - b * (H_ * W_);
    const int i  = ij / W_;
    const int j  = ij - i * W_;

    int si = i - (K >> 1); if (si < 0) si = 0; if (si > H_ - K) si = H_ - K;
    int sj = j - (K >> 1); if (sj < 0) sj = 0; if (sj > W_ - K) sj = W_ - K;

    const int cbase = g * 192 + h * 32;
    const float* qp = qkv + (size_t)pix * QKVC + cbase;

    float q[32];
    #pragma unroll
    for (int d = 0; d < 32; d += 4) {
        float4 t = *(const float4*)(qp + d);
        q[d + 0] = t.x * SCALE; q[d + 1] = t.y * SCALE;
        q[d + 2] = t.z * SCALE; q[d + 3] = t.w * SCALE;
    }

    float y[32];
    #pragma unroll
    for (int d = 0; d < 32; ++d) y[d] = 0.f;
    float l = 0.f;

    for (int wi = 0; wi < K; ++wi) {
        const float* rp = qkv + (size_t)((b * H_ + si + wi) * W_ + sj) * QKVC + cbase + 64;
        for (int wj = 0; wj < K; ++wj) {
            const float* kp = rp + wj * QKVC;
            float dot = 0.f;
            #pragma unroll
            for (int d = 0; d < 32; d += 4) {
                float4 kk = *(const float4*)(kp + d);
                dot += q[d] * kk.x + q[d + 1] * kk.y + q[d + 2] * kk.z + q[d + 3] * kk.w;
            }
            float e = __expf(dot);
            l += e;
            #pragma unroll
            for (int d = 0; d < 32; d += 4) {
                float4 vv = *(const float4*)(kp + 64 + d);
                y[d + 0] += e * vv.x; y[d + 1] += e * vv.y;
                y[d + 2] += e * vv.z; y[d + 3] += e * vv.w;
            }
        }
    }

    const float inv = 1.f / l;
    float* op = out + (size_t)pix * C_ + g * 64 + h * 32;
    #pragma unroll
    for (int d = 0; d < 32; d += 4) {
        float4 o;
        o.x = y[d + 0] * inv; o.y = y[d + 1] * inv;
        o.z = y[d + 2] * inv; o.w = y[d + 3] * inv;
        *(float4*)(op + d) = o;
    }
}

// ---------------------------------------------------------------------------
extern "C" void kernel_launch(void* const* d_in, const int* in_sizes, int n_in,
                              void* d_out, int out_size, void* d_ws, size_t ws_size,
                              hipStream_t stream)
{
    const float* x      = (const float*)d_in[0];
    const float* w_qkv  = (const float*)d_in[1];
    const float* b_qkv  = (const float*)d_in[2];
    const float* w_proj = (const float*)d_in[3];
    const float* b_proj = (const float*)d_in[4];
    float* out = (float*)d_out;

    float* qkv  = (float*)d_ws;                       // NPIX * 576 floats (84.9 MB)
    float* attn = qkv + (size_t)NPIX * QKVC;          // NPIX * 192 floats (28.3 MB)

    // 1) qkv = x @ w_qkv + b_qkv          (36864 x 192) @ (192 x 576)
    gemm_bias_kernel<<<(NPIX / 64) * (QKVC / 64), 256, 0, stream>>>(
        x, w_qkv, b_qkv, qkv, NPIX, QKVC, C_);

    // 2) neighborhood attention, 3 groups x 2 heads
    na2d_kernel<<<6 * 144, 256, 0, stream>>>(qkv, attn);

    // 3) out = attn @ w_proj + b_proj     (36864 x 192) @ (192 x 192)
    gemm_bias_kernel<<<(NPIX / 64) * (C_ / 64), 256, 0, stream>>>(
        attn, w_proj, b_proj, out, NPIX, C_, C_);
}

// Round 2
// 368.790 us; speedup vs baseline: 2.7607x; 2.7607x over previous
//
#include <hip/hip_runtime.h>
#include <cstddef>

// Problem constants
constexpr int B_ = 4, H_ = 96, W_ = 96, C_ = 192, QKVC = 576;
constexpr int NPIX = B_ * H_ * W_;           // 36864
constexpr float SCALE = 0.17677669529663689f; // 32^-0.5

// ---------------------------------------------------------------------------
// Tiled fp32 GEMM: C[M,N] = A[M,K] @ B[K,N] + bias[N]
// BM=BN=BK=64, 256 threads, 4x4 microtile per thread.
// ---------------------------------------------------------------------------
__global__ __launch_bounds__(256) void gemm_bias_kernel(
    const float* __restrict__ A, const float* __restrict__ B,
    const float* __restrict__ bias, float* __restrict__ C,
    int M, int N, int K)
{
    __shared__ float As[64][68];   // [m][k], +4 pad breaks stride-64 bank conflicts
    __shared__ float Bs[64][64];   // [k][n]

    const int tid = threadIdx.x;
    const int tx = tid & 15;       // n direction (16)
    const int ty = tid >> 4;       // m direction (16)
    const int ntiles = N >> 6;
    const int m0 = (blockIdx.x / ntiles) << 6;
    const int n0 = (blockIdx.x % ntiles) << 6;

    float acc[4][4];
    #pragma unroll
    for (int i = 0; i < 4; ++i)
        #pragma unroll
        for (int j = 0; j < 4; ++j) acc[i][j] = 0.f;

    for (int k0 = 0; k0 < K; k0 += 64) {
        #pragma unroll
        for (int it = 0; it < 4; ++it) {
            int idx = it * 256 + tid;
            int r = idx >> 4;
            int c4 = (idx & 15) << 2;
            float4 va = *(const float4*)(A + (size_t)(m0 + r) * K + k0 + c4);
            *(float4*)(&As[r][c4]) = va;
        }
        #pragma unroll
        for (int it = 0; it < 4; ++it) {
            int idx = it * 256 + tid;
            int r = idx >> 4;
            int c4 = (idx & 15) << 2;
            float4 vb = *(const float4*)(B + (size_t)(k0 + r) * N + n0 + c4);
            *(float4*)(&Bs[r][c4]) = vb;
        }
        __syncthreads();

        #pragma unroll 8
        for (int k = 0; k < 64; ++k) {
            float a0 = As[ty * 4 + 0][k];
            float a1 = As[ty * 4 + 1][k];
            float a2 = As[ty * 4 + 2][k];
            float a3 = As[ty * 4 + 3][k];
            float4 b4 = *(const float4*)(&Bs[k][tx * 4]);
            acc[0][0] += a0 * b4.x; acc[0][1] += a0 * b4.y; acc[0][2] += a0 * b4.z; acc[0][3] += a0 * b4.w;
            acc[1][0] += a1 * b4.x; acc[1][1] += a1 * b4.y; acc[1][2] += a1 * b4.z; acc[1][3] += a1 * b4.w;
            acc[2][0] += a2 * b4.x; acc[2][1] += a2 * b4.y; acc[2][2] += a2 * b4.z; acc[2][3] += a2 * b4.w;
            acc[3][0] += a3 * b4.x; acc[3][1] += a3 * b4.y; acc[3][2] += a3 * b4.z; acc[3][3] += a3 * b4.w;
        }
        __syncthreads();
    }

    float4 bb = *(const float4*)(bias + n0 + tx * 4);
    #pragma unroll
    for (int i = 0; i < 4; ++i) {
        float4 o;
        o.x = acc[i][0] + bb.x;
        o.y = acc[i][1] + bb.y;
        o.z = acc[i][2] + bb.z;
        o.w = acc[i][3] + bb.w;
        *(float4*)(C + (size_t)(m0 + ty * 4 + i) * N + n0 + tx * 4) = o;
    }
}

// ---------------------------------------------------------------------------
// Neighborhood attention, LDS-staged.
// Block = (group g, batch b, row-pair p): 576 blocks, 192 threads (j in 0..95,
// h in 0..1). Each thread computes output pixels (i0,j) and (i1,j) for head h.
// Window-row start si is uniform across a row, so the block stages full
// 96-pixel k/v rows (one group's 128 channels) into LDS once per unique
// window row of the pair (<= K+1 stages), planar float4 layout [f][pix]
// padded to 97 to spread bank groups.
// ---------------------------------------------------------------------------
__global__ __launch_bounds__(192) void na2d_kernel(
    const float* __restrict__ qkv, float* __restrict__ out)
{
    __shared__ float4 smem[32 * 97];   // 49.7 KB: f=0..15 k (h0,h1), 16..31 v

    int bp = blockIdx.x;
    const int g = bp % 3; bp /= 3;       // interleave groups for tail balance
    const int b = bp / 48;
    const int p = bp % 48;
    const int i0 = 2 * p, i1 = i0 + 1;
    const int K = 7 + 2 * g;
    const int c = K >> 1;

    const int tid = threadIdx.x;
    const int j = tid % 96;
    const int h = tid / 96;
    const int h8 = h * 8;

    int si0 = i0 - c; if (si0 < 0) si0 = 0; if (si0 > H_ - K) si0 = H_ - K;
    int si1 = i1 - c; if (si1 < 0) si1 = 0; if (si1 > H_ - K) si1 = H_ - K;
    const int d01 = si1 - si0;           // 0 or 1
    const int nr = d01 + K;              // unique window rows for the pair

    int sj = j - c; if (sj < 0) sj = 0; if (sj > W_ - K) sj = W_ - K;

    // q for both rows (scaled)
    const float* q0p = qkv + (size_t)((b * H_ + i0) * W_ + j) * QKVC + g * 192 + h * 32;
    const float* q1p = q0p + (size_t)W_ * QKVC;
    float4 q0[8], q1[8], y0[8], y1[8];
    #pragma unroll
    for (int d4 = 0; d4 < 8; ++d4) {
        float4 t0 = ((const float4*)q0p)[d4];
        float4 t1 = ((const float4*)q1p)[d4];
        t0.x *= SCALE; t0.y *= SCALE; t0.z *= SCALE; t0.w *= SCALE;
        t1.x *= SCALE; t1.y *= SCALE; t1.z *= SCALE; t1.w *= SCALE;
        q0[d4] = t0; q1[d4] = t1;
        y0[d4] = make_float4(0.f, 0.f, 0.f, 0.f);
        y1[d4] = make_float4(0.f, 0.f, 0.f, 0.f);
    }
    float l0 = 0.f, l1 = 0.f;

    const float4* qkv4 = (const float4*)qkv;

    for (int t = 0; t < nr; ++t) {
        const int r = si0 + t;
        __syncthreads();   // previous iteration's readers done before overwrite
        // stage row r: 96 pixels x 32 float4 (k/v of group g), coalesced reads
        const size_t rowbase = (size_t)(b * H_ + r) * W_ * 144;  // f4 units
        #pragma unroll
        for (int it = 0; it < 16; ++it) {
            int idx = it * 192 + tid;
            int pix = idx >> 5;
            int f = idx & 31;
            smem[f * 97 + pix] = qkv4[rowbase + (size_t)pix * 144 + g * 48 + 16 + f];
        }
        __syncthreads();

        const bool a0 = (t < K);        // row0 uses window rows t=0..K-1
        const bool a1 = (t >= d01);     // row1 uses t=d01..d01+K-1
        for (int wj = 0; wj < K; ++wj) {
            const int col = sj + wj;
            float dot0 = 0.f, dot1 = 0.f;
            #pragma unroll
            for (int d4 = 0; d4 < 8; ++d4) {
                float4 kk = smem[(h8 + d4) * 97 + col];
                float4 a = q0[d4], bq = q1[d4];
                dot0 += a.x * kk.x + a.y * kk.y + a.z * kk.z + a.w * kk.w;
                dot1 += bq.x * kk.x + bq.y * kk.y + bq.z * kk.z + bq.w * kk.w;
            }
            const float e0 = a0 ? __expf(dot0) : 0.f;
            const float e1 = a1 ? __expf(dot1) : 0.f;
            l0 += e0; l1 += e1;
            #pragma unroll
            for (int d4 = 0; d4 < 8; ++d4) {
                float4 vv = smem[(16 + h8 + d4) * 97 + col];
                y0[d4].x += e0 * vv.x; y0[d4].y += e0 * vv.y;
                y0[d4].z += e0 * vv.z; y0[d4].w += e0 * vv.w;
                y1[d4].x += e1 * vv.x; y1[d4].y += e1 * vv.y;
                y1[d4].z += e1 * vv.z; y1[d4].w += e1 * vv.w;
            }
        }
    }

    const float inv0 = 1.f / l0, inv1 = 1.f / l1;
    float* o0 = out + (size_t)((b * H_ + i0) * W_ + j) * C_ + g * 64 + h * 32;
    float* o1 = o0 + (size_t)W_ * C_;
    #pragma unroll
    for (int d4 = 0; d4 < 8; ++d4) {
        float4 w0, w1;
        w0.x = y0[d4].x * inv0; w0.y = y0[d4].y * inv0;
        w0.z = y0[d4].z * inv0; w0.w = y0[d4].w * inv0;
        w1.x = y1[d4].x * inv1; w1.y = y1[d4].y * inv1;
        w1.z = y1[d4].z * inv1; w1.w = y1[d4].w * inv1;
        ((float4*)o0)[d4] = w0;
        ((float4*)o1)[d4] = w1;
    }
}

// ---------------------------------------------------------------------------
extern "C" void kernel_launch(void* const* d_in, const int* in_sizes, int n_in,
                              void* d_out, int out_size, void* d_ws, size_t ws_size,
                              hipStream_t stream)
{
    const float* x      = (const float*)d_in[0];
    const float* w_qkv  = (const float*)d_in[1];
    const float* b_qkv  = (const float*)d_in[2];
    const float* w_proj = (const float*)d_in[3];
    const float* b_proj = (const float*)d_in[4];
    float* out = (float*)d_out;

    float* qkv  = (float*)d_ws;                       // NPIX * 576 floats (84.9 MB)
    float* attn = qkv + (size_t)NPIX * QKVC;          // NPIX * 192 floats (28.3 MB)

    // 1) qkv = x @ w_qkv + b_qkv          (36864 x 192) @ (192 x 576)
    gemm_bias_kernel<<<(NPIX / 64) * (QKVC / 64), 256, 0, stream>>>(
        x, w_qkv, b_qkv, qkv, NPIX, QKVC, C_);

    // 2) neighborhood attention: 3 groups x 4 batches x 48 row-pairs
    na2d_kernel<<<576, 192, 0, stream>>>(qkv, attn);

    // 3) out = attn @ w_proj + b_proj     (36864 x 192) @ (192 x 192)
    gemm_bias_kernel<<<(NPIX / 64) * (C_ / 64), 256, 0, stream>>>(
        attn, w_proj, b_proj, out, NPIX, C_, C_);
}

// Round 3
// 288.784 us; speedup vs baseline: 3.5255x; 1.2770x over previous
//
#include <hip/hip_runtime.h>
#include <cstddef>

// Problem constants
constexpr int B_ = 4, H_ = 96, W_ = 96, C_ = 192, QKVC = 576;
constexpr int NPIX = B_ * H_ * W_;           // 36864
constexpr float SCALE = 0.17677669529663689f; // 32^-0.5

typedef __attribute__((ext_vector_type(8))) short bf16x8;
typedef __attribute__((ext_vector_type(4))) float f32x4;
typedef unsigned short ushort_t;

__device__ __forceinline__ unsigned short f2bf(float f) {
    unsigned int u = __builtin_bit_cast(unsigned int, f);
    u += 0x7fffu + ((u >> 16) & 1u);       // round-to-nearest-even
    return (unsigned short)(u >> 16);
}
__device__ __forceinline__ float bf2f(unsigned short h) {
    unsigned int u = ((unsigned int)h) << 16;
    return __builtin_bit_cast(float, u);
}
__device__ __forceinline__ unsigned int pack2(unsigned short a, unsigned short b) {
    return (unsigned int)a | ((unsigned int)b << 16);
}

// ---------------------------------------------------------------------------
// MFMA bf16 GEMM: C[M,N] = A[M,K] @ B[K,N] + bias[N], fp32 in/out.
// PASSES=1: plain bf16 (A,B rounded). PASSES=3: split bf16 (hi/lo),
// acc += Ah*Bh + Ah*Bl + Al*Bh  (fp32-like accuracy).
// Block: 64x64 tile, 256 threads = 4 waves in 2x2, each wave 2x2 mfma tiles.
// K % 64 == 0. LDS fragment-order: As[kc][m][j] holds A[m][kc*8+j] (bf16),
// so a lane's 8-elem fragment is one 16B chunk, lane-linear ds_read_b128.
// ---------------------------------------------------------------------------
template<int PASSES>
__global__ __launch_bounds__(256) void gemm_mfma_kernel(
    const float* __restrict__ A, const float* __restrict__ B,
    const float* __restrict__ bias, float* __restrict__ C,
    int M, int N, int K)
{
    constexpr int NP = (PASSES == 3) ? 2 : 1;
    __shared__ ushort_t As[NP][8][64][8];   // [hi/lo][kc][m][j]
    __shared__ ushort_t Bs[NP][8][64][8];   // [hi/lo][kc][n][j]

    const int tid = threadIdx.x;
    const int lane = tid & 63;
    const int w = tid >> 6;
    const int wm = (w & 1) * 32;
    const int wn = (w >> 1) * 32;
    const int fm = lane & 15;
    const int fq = lane >> 4;

    const int ntiles = N >> 6;
    const int m0 = (blockIdx.x / ntiles) << 6;
    const int n0 = (blockIdx.x % ntiles) << 6;

    f32x4 acc[2][2];
    #pragma unroll
    for (int mi = 0; mi < 2; ++mi)
        #pragma unroll
        for (int ni = 0; ni < 2; ++ni)
            acc[mi][ni] = (f32x4){0.f, 0.f, 0.f, 0.f};

    for (int k0 = 0; k0 < K; k0 += 64) {
        __syncthreads();
        // ---- stage A tile (64 m x 64 k), coalesced float4 reads ----
        #pragma unroll
        for (int it = 0; it < 4; ++it) {
            int idx = it * 256 + tid;
            int m = idx >> 4;
            int kq4 = idx & 15;                 // float4 index along k
            float4 v = *(const float4*)(A + (size_t)(m0 + m) * K + k0 + kq4 * 4);
            unsigned short h0 = f2bf(v.x), h1 = f2bf(v.y), h2 = f2bf(v.z), h3 = f2bf(v.w);
            uint2 p; p.x = pack2(h0, h1); p.y = pack2(h2, h3);
            *(uint2*)&As[0][kq4 >> 1][m][(kq4 & 1) * 4] = p;
            if (PASSES == 3) {
                unsigned short l0 = f2bf(v.x - bf2f(h0));
                unsigned short l1 = f2bf(v.y - bf2f(h1));
                unsigned short l2 = f2bf(v.z - bf2f(h2));
                unsigned short l3 = f2bf(v.w - bf2f(h3));
                uint2 q; q.x = pack2(l0, l1); q.y = pack2(l2, l3);
                *(uint2*)&As[1][kq4 >> 1][m][(kq4 & 1) * 4] = q;
            }
        }
        // ---- stage B tile (64 k x 64 n): n-coalesced scalar reads,
        //      lane-linear b128 LDS writes ----
        {
            const int n = tid & 63;
            const int kb = (tid >> 6) * 16;
            float vals[16];
            #pragma unroll
            for (int i = 0; i < 16; ++i)
                vals[i] = B[(size_t)(k0 + kb + i) * N + n0 + n];
            #pragma unroll
            for (int c = 0; c < 2; ++c) {
                uint4 ph;
                ph.x = pack2(f2bf(vals[c*8+0]), f2bf(vals[c*8+1]));
                ph.y = pack2(f2bf(vals[c*8+2]), f2bf(vals[c*8+3]));
                ph.z = pack2(f2bf(vals[c*8+4]), f2bf(vals[c*8+5]));
                ph.w = pack2(f2bf(vals[c*8+6]), f2bf(vals[c*8+7]));
                *(uint4*)&Bs[0][(kb >> 3) + c][n][0] = ph;
                if (PASSES == 3) {
                    uint4 pl;
                    pl.x = pack2(f2bf(vals[c*8+0] - bf2f((unsigned short)(ph.x & 0xffff))),
                                 f2bf(vals[c*8+1] - bf2f((unsigned short)(ph.x >> 16))));
                    pl.y = pack2(f2bf(vals[c*8+2] - bf2f((unsigned short)(ph.y & 0xffff))),
                                 f2bf(vals[c*8+3] - bf2f((unsigned short)(ph.y >> 16))));
                    pl.z = pack2(f2bf(vals[c*8+4] - bf2f((unsigned short)(ph.z & 0xffff))),
                                 f2bf(vals[c*8+5] - bf2f((unsigned short)(ph.z >> 16))));
                    pl.w = pack2(f2bf(vals[c*8+6] - bf2f((unsigned short)(ph.w & 0xffff))),
                                 f2bf(vals[c*8+7] - bf2f((unsigned short)(ph.w >> 16))));
                    *(uint4*)&Bs[1][(kb >> 3) + c][n][0] = pl;
                }
            }
        }
        __syncthreads();

        // ---- compute: 2 k-chunks of 32 ----
        #pragma unroll
        for (int kt2 = 0; kt2 < 2; ++kt2) {
            const int kc = kt2 * 4 + fq;
            bf16x8 ah[2], bh[2];
            ah[0] = *(const bf16x8*)&As[0][kc][wm + fm][0];
            ah[1] = *(const bf16x8*)&As[0][kc][wm + 16 + fm][0];
            bh[0] = *(const bf16x8*)&Bs[0][kc][wn + fm][0];
            bh[1] = *(const bf16x8*)&Bs[0][kc][wn + 16 + fm][0];
            #pragma unroll
            for (int mi = 0; mi < 2; ++mi)
                #pragma unroll
                for (int ni = 0; ni < 2; ++ni)
                    acc[mi][ni] = __builtin_amdgcn_mfma_f32_16x16x32_bf16(
                        ah[mi], bh[ni], acc[mi][ni], 0, 0, 0);
            if (PASSES == 3) {
                bf16x8 al[2], bl[2];
                al[0] = *(const bf16x8*)&As[1][kc][wm + fm][0];
                al[1] = *(const bf16x8*)&As[1][kc][wm + 16 + fm][0];
                bl[0] = *(const bf16x8*)&Bs[1][kc][wn + fm][0];
                bl[1] = *(const bf16x8*)&Bs[1][kc][wn + 16 + fm][0];
                #pragma unroll
                for (int mi = 0; mi < 2; ++mi)
                    #pragma unroll
                    for (int ni = 0; ni < 2; ++ni) {
                        acc[mi][ni] = __builtin_amdgcn_mfma_f32_16x16x32_bf16(
                            ah[mi], bl[ni], acc[mi][ni], 0, 0, 0);
                        acc[mi][ni] = __builtin_amdgcn_mfma_f32_16x16x32_bf16(
                            al[mi], bh[ni], acc[mi][ni], 0, 0, 0);
                    }
            }
        }
    }

    // ---- epilogue: C/D layout col=lane&15, row=fq*4+reg ----
    #pragma unroll
    for (int ni = 0; ni < 2; ++ni) {
        const int col = n0 + wn + ni * 16 + fm;
        const float bv = bias[col];
        #pragma unroll
        for (int mi = 0; mi < 2; ++mi) {
            const int rbase = m0 + wm + mi * 16 + fq * 4;
            #pragma unroll
            for (int r = 0; r < 4; ++r)
                C[(size_t)(rbase + r) * N + col] = acc[mi][ni][r] + bv;
        }
    }
}

// ---------------------------------------------------------------------------
// Neighborhood attention, LDS-staged (unchanged from R2).
// ---------------------------------------------------------------------------
__global__ __launch_bounds__(192) void na2d_kernel(
    const float* __restrict__ qkv, float* __restrict__ out)
{
    __shared__ float4 smem[32 * 97];   // 49.7 KB: f=0..15 k (h0,h1), 16..31 v

    int bp = blockIdx.x;
    const int g = bp % 3; bp /= 3;
    const int b = bp / 48;
    const int p = bp % 48;
    const int i0 = 2 * p, i1 = i0 + 1;
    const int K = 7 + 2 * g;
    const int c = K >> 1;

    const int tid = threadIdx.x;
    const int j = tid % 96;
    const int h = tid / 96;
    const int h8 = h * 8;

    int si0 = i0 - c; if (si0 < 0) si0 = 0; if (si0 > H_ - K) si0 = H_ - K;
    int si1 = i1 - c; if (si1 < 0) si1 = 0; if (si1 > H_ - K) si1 = H_ - K;
    const int d01 = si1 - si0;
    const int nr = d01 + K;

    int sj = j - c; if (sj < 0) sj = 0; if (sj > W_ - K) sj = W_ - K;

    const float* q0p = qkv + (size_t)((b * H_ + i0) * W_ + j) * QKVC + g * 192 + h * 32;
    const float* q1p = q0p + (size_t)W_ * QKVC;
    float4 q0[8], q1[8], y0[8], y1[8];
    #pragma unroll
    for (int d4 = 0; d4 < 8; ++d4) {
        float4 t0 = ((const float4*)q0p)[d4];
        float4 t1 = ((const float4*)q1p)[d4];
        t0.x *= SCALE; t0.y *= SCALE; t0.z *= SCALE; t0.w *= SCALE;
        t1.x *= SCALE; t1.y *= SCALE; t1.z *= SCALE; t1.w *= SCALE;
        q0[d4] = t0; q1[d4] = t1;
        y0[d4] = make_float4(0.f, 0.f, 0.f, 0.f);
        y1[d4] = make_float4(0.f, 0.f, 0.f, 0.f);
    }
    float l0 = 0.f, l1 = 0.f;

    const float4* qkv4 = (const float4*)qkv;

    for (int t = 0; t < nr; ++t) {
        const int r = si0 + t;
        __syncthreads();
        const size_t rowbase = (size_t)(b * H_ + r) * W_ * 144;
        #pragma unroll
        for (int it = 0; it < 16; ++it) {
            int idx = it * 192 + tid;
            int pix = idx >> 5;
            int f = idx & 31;
            smem[f * 97 + pix] = qkv4[rowbase + (size_t)pix * 144 + g * 48 + 16 + f];
        }
        __syncthreads();

        const bool a0 = (t < K);
        const bool a1 = (t >= d01);
        for (int wj = 0; wj < K; ++wj) {
            const int col = sj + wj;
            float dot0 = 0.f, dot1 = 0.f;
            #pragma unroll
            for (int d4 = 0; d4 < 8; ++d4) {
                float4 kk = smem[(h8 + d4) * 97 + col];
                float4 a = q0[d4], bq = q1[d4];
                dot0 += a.x * kk.x + a.y * kk.y + a.z * kk.z + a.w * kk.w;
                dot1 += bq.x * kk.x + bq.y * kk.y + bq.z * kk.z + bq.w * kk.w;
            }
            const float e0 = a0 ? __expf(dot0) : 0.f;
            const float e1 = a1 ? __expf(dot1) : 0.f;
            l0 += e0; l1 += e1;
            #pragma unroll
            for (int d4 = 0; d4 < 8; ++d4) {
                float4 vv = smem[(16 + h8 + d4) * 97 + col];
                y0[d4].x += e0 * vv.x; y0[d4].y += e0 * vv.y;
                y0[d4].z += e0 * vv.z; y0[d4].w += e0 * vv.w;
                y1[d4].x += e1 * vv.x; y1[d4].y += e1 * vv.y;
                y1[d4].z += e1 * vv.z; y1[d4].w += e1 * vv.w;
            }
        }
    }

    const float inv0 = 1.f / l0, inv1 = 1.f / l1;
    float* o0 = out + (size_t)((b * H_ + i0) * W_ + j) * C_ + g * 64 + h * 32;
    float* o1 = o0 + (size_t)W_ * C_;
    #pragma unroll
    for (int d4 = 0; d4 < 8; ++d4) {
        float4 w0, w1;
        w0.x = y0[d4].x * inv0; w0.y = y0[d4].y * inv0;
        w0.z = y0[d4].z * inv0; w0.w = y0[d4].w * inv0;
        w1.x = y1[d4].x * inv1; w1.y = y1[d4].y * inv1;
        w1.z = y1[d4].z * inv1; w1.w = y1[d4].w * inv1;
        ((float4*)o0)[d4] = w0;
        ((float4*)o1)[d4] = w1;
    }
}

// ---------------------------------------------------------------------------
extern "C" void kernel_launch(void* const* d_in, const int* in_sizes, int n_in,
                              void* d_out, int out_size, void* d_ws, size_t ws_size,
                              hipStream_t stream)
{
    const float* x      = (const float*)d_in[0];
    const float* w_qkv  = (const float*)d_in[1];
    const float* b_qkv  = (const float*)d_in[2];
    const float* w_proj = (const float*)d_in[3];
    const float* b_proj = (const float*)d_in[4];
    float* out = (float*)d_out;

    float* qkv  = (float*)d_ws;                       // NPIX * 576 floats (84.9 MB)
    float* attn = qkv + (size_t)NPIX * QKVC;          // NPIX * 192 floats (28.3 MB)

    // 1) qkv = x @ w_qkv + b_qkv   — plain bf16 MFMA (error attenuated downstream)
    gemm_mfma_kernel<1><<<(NPIX / 64) * (QKVC / 64), 256, 0, stream>>>(
        x, w_qkv, b_qkv, qkv, NPIX, QKVC, C_);

    // 2) neighborhood attention: 3 groups x 4 batches x 48 row-pairs
    na2d_kernel<<<576, 192, 0, stream>>>(qkv, attn);

    // 3) out = attn @ w_proj + b_proj — split-bf16 x3 MFMA (direct output path)
    gemm_mfma_kernel<3><<<(NPIX / 64) * (C_ / 64), 256, 0, stream>>>(
        attn, w_proj, b_proj, out, NPIX, C_, C_);
}

// Round 4
// 269.300 us; speedup vs baseline: 3.7806x; 1.0724x over previous
//
#include <hip/hip_runtime.h>
#include <cstddef>

// Problem constants
constexpr int B_ = 4, H_ = 96, W_ = 96, C_ = 192, QKVC = 576;
constexpr int NPIX = B_ * H_ * W_;           // 36864
constexpr float SCALE = 0.17677669529663689f; // 32^-0.5

typedef __attribute__((ext_vector_type(8))) short bf16x8;
typedef __attribute__((ext_vector_type(4))) float f32x4;
typedef unsigned short ushort_t;

__device__ __forceinline__ unsigned short f2bf(float f) {
    unsigned int u = __builtin_bit_cast(unsigned int, f);
    u += 0x7fffu + ((u >> 16) & 1u);       // round-to-nearest-even
    return (unsigned short)(u >> 16);
}
__device__ __forceinline__ float bf2f(unsigned short h) {
    unsigned int u = ((unsigned int)h) << 16;
    return __builtin_bit_cast(float, u);
}
__device__ __forceinline__ unsigned int pack2(unsigned short a, unsigned short b) {
    return (unsigned int)a | ((unsigned int)b << 16);
}

// ---------------------------------------------------------------------------
// convert_x: fp32 -> bf16, one float4 -> 8B per thread.
// ---------------------------------------------------------------------------
__global__ __launch_bounds__(256) void convert_x_kernel(
    const float* __restrict__ x, ushort_t* __restrict__ xh, int n4)
{
    int i = blockIdx.x * 256 + threadIdx.x;
    if (i >= n4) return;
    float4 v = ((const float4*)x)[i];
    uint2 p;
    p.x = pack2(f2bf(v.x), f2bf(v.y));
    p.y = pack2(f2bf(v.z), f2bf(v.w));
    ((uint2*)xh)[i] = p;
}

// ---------------------------------------------------------------------------
// convert_w: w_qkv[192][576] -> wqt[576][192] bf16;
//            w_proj[192][192] -> wpt_h/wpt_l[192][192] (split hi/lo bf16).
// ---------------------------------------------------------------------------
__global__ __launch_bounds__(256) void convert_w_kernel(
    const float* __restrict__ w_qkv, const float* __restrict__ w_proj,
    ushort_t* __restrict__ wqt, ushort_t* __restrict__ wpt_h,
    ushort_t* __restrict__ wpt_l)
{
    int idx = blockIdx.x * 256 + threadIdx.x;
    if (idx < 576 * 192) {
        int n = idx / 192, k = idx - n * 192;
        wqt[idx] = f2bf(w_qkv[(size_t)k * 576 + n]);
    } else {
        int i2 = idx - 576 * 192;
        if (i2 < 192 * 192) {
            int n = i2 / 192, k = i2 - n * 192;
            float v = w_proj[(size_t)k * 192 + n];
            unsigned short h = f2bf(v);
            wpt_h[i2] = h;
            wpt_l[i2] = f2bf(v - bf2f(h));
        }
    }
}

// ---------------------------------------------------------------------------
// MFMA bf16 GEMM, tile 64(M) x 192(N) x 64(K-step), 256 threads = 4 waves.
// Wave tile 32x96 = 2x6 mfma tiles of 16x16, K=16x16x32 bf16 mfma.
// B is pre-transposed bf16: Bt[n][k] (+ low plane if SPLIT).
// SPLIT=false: A is bf16 plane [M][K], 1 pass.
// SPLIT=true : A is fp32 [M][K], hi/lo split in staging; 3 passes
//              (Ah*Bh + Ah*Bl + Al*Bh) for fp32-like accuracy.
// LDS fragment-order with XOR swizzle: chunk(kc, i) at kc*DIM + (i ^ kc),
// each chunk = 8 contiguous k bf16 = 16B; applied on write and read alike.
// ---------------------------------------------------------------------------
template<bool SPLIT>
__global__ __launch_bounds__(256) void gemm_mfma2_kernel(
    const void* __restrict__ Aptr,
    const ushort_t* __restrict__ Bt_h, const ushort_t* __restrict__ Bt_l,
    const float* __restrict__ bias, float* __restrict__ C,
    int M, int N, int K)
{
    constexpr int NP = SPLIT ? 2 : 1;
    __shared__ __align__(16) ushort_t As[NP][8 * 64 * 8];
    __shared__ __align__(16) ushort_t Bs[NP][8 * 192 * 8];

    const int tid = threadIdx.x;
    const int lane = tid & 63;
    const int w = tid >> 6;
    const int wm = (w & 1) * 32;
    const int wn = (w >> 1) * 96;
    const int fm = lane & 15;
    const int fq = lane >> 4;

    const int ntiles = N / 192;
    const int m0 = (blockIdx.x / ntiles) * 64;
    const int n0 = (blockIdx.x % ntiles) * 192;

    f32x4 acc[2][6];
    #pragma unroll
    for (int mi = 0; mi < 2; ++mi)
        #pragma unroll
        for (int ni = 0; ni < 6; ++ni)
            acc[mi][ni] = (f32x4){0.f, 0.f, 0.f, 0.f};

    for (int k0 = 0; k0 < K; k0 += 64) {
        __syncthreads();
        // ---- stage A ----
        if constexpr (!SPLIT) {
            const ushort_t* Ah = (const ushort_t*)Aptr;
            #pragma unroll
            for (int it = 0; it < 2; ++it) {
                int idx = it * 256 + tid;
                int m = idx >> 3, kc = idx & 7;
                uint4 v = *(const uint4*)(Ah + (size_t)(m0 + m) * K + k0 + kc * 8);
                int phys = kc * 64 + (m ^ kc);
                *(uint4*)(&As[0][0] + phys * 8) = v;
            }
        } else {
            const float* Af = (const float*)Aptr;
            #pragma unroll
            for (int it = 0; it < 4; ++it) {
                int idx = it * 256 + tid;
                int m = idx >> 4, kq4 = idx & 15;
                float4 v = *(const float4*)(Af + (size_t)(m0 + m) * K + k0 + kq4 * 4);
                unsigned short h0 = f2bf(v.x), h1 = f2bf(v.y), h2 = f2bf(v.z), h3 = f2bf(v.w);
                uint2 ph; ph.x = pack2(h0, h1); ph.y = pack2(h2, h3);
                uint2 pl;
                pl.x = pack2(f2bf(v.x - bf2f(h0)), f2bf(v.y - bf2f(h1)));
                pl.y = pack2(f2bf(v.z - bf2f(h2)), f2bf(v.w - bf2f(h3)));
                int kc = kq4 >> 1, half = kq4 & 1;
                int phys = kc * 64 + (m ^ kc);
                *(uint2*)(&As[0][0] + phys * 8 + half * 4) = ph;
                *(uint2*)(&As[NP - 1][0] + phys * 8 + half * 4) = pl;
            }
        }
        // ---- stage B (contiguous bf16 chunks from Bt[n][k]) ----
        #pragma unroll
        for (int it = 0; it < 6; ++it) {
            int idx = it * 256 + tid;
            int n = idx >> 3, kc = idx & 7;
            int phys = kc * 192 + (n ^ kc);
            *(uint4*)(&Bs[0][0] + phys * 8) =
                *(const uint4*)(Bt_h + (size_t)(n0 + n) * K + k0 + kc * 8);
            if constexpr (SPLIT)
                *(uint4*)(&Bs[NP - 1][0] + phys * 8) =
                    *(const uint4*)(Bt_l + (size_t)(n0 + n) * K + k0 + kc * 8);
        }
        __syncthreads();

        // ---- compute ----
        #pragma unroll
        for (int kt2 = 0; kt2 < 2; ++kt2) {
            const int kc = kt2 * 4 + fq;
            bf16x8 ah[2], bh[6];
            #pragma unroll
            for (int mi = 0; mi < 2; ++mi)
                ah[mi] = *(const bf16x8*)(&As[0][0] + (kc * 64 + ((wm + mi * 16 + fm) ^ kc)) * 8);
            #pragma unroll
            for (int ni = 0; ni < 6; ++ni)
                bh[ni] = *(const bf16x8*)(&Bs[0][0] + (kc * 192 + ((wn + ni * 16 + fm) ^ kc)) * 8);
            #pragma unroll
            for (int mi = 0; mi < 2; ++mi)
                #pragma unroll
                for (int ni = 0; ni < 6; ++ni)
                    acc[mi][ni] = __builtin_amdgcn_mfma_f32_16x16x32_bf16(
                        ah[mi], bh[ni], acc[mi][ni], 0, 0, 0);
            if constexpr (SPLIT) {
                bf16x8 al[2], bl[6];
                #pragma unroll
                for (int mi = 0; mi < 2; ++mi)
                    al[mi] = *(const bf16x8*)(&As[NP - 1][0] + (kc * 64 + ((wm + mi * 16 + fm) ^ kc)) * 8);
                #pragma unroll
                for (int ni = 0; ni < 6; ++ni)
                    bl[ni] = *(const bf16x8*)(&Bs[NP - 1][0] + (kc * 192 + ((wn + ni * 16 + fm) ^ kc)) * 8);
                #pragma unroll
                for (int mi = 0; mi < 2; ++mi)
                    #pragma unroll
                    for (int ni = 0; ni < 6; ++ni) {
                        acc[mi][ni] = __builtin_amdgcn_mfma_f32_16x16x32_bf16(
                            ah[mi], bl[ni], acc[mi][ni], 0, 0, 0);
                        acc[mi][ni] = __builtin_amdgcn_mfma_f32_16x16x32_bf16(
                            al[mi], bh[ni], acc[mi][ni], 0, 0, 0);
                    }
            }
        }
    }

    // ---- epilogue: C/D layout col=lane&15, row=fq*4+reg ----
    #pragma unroll
    for (int ni = 0; ni < 6; ++ni) {
        const int col = n0 + wn + ni * 16 + fm;
        const float bv = bias[col];
        #pragma unroll
        for (int mi = 0; mi < 2; ++mi) {
            const int rbase = m0 + wm + mi * 16 + fq * 4;
            #pragma unroll
            for (int r = 0; r < 4; ++r)
                C[(size_t)(rbase + r) * N + col] = acc[mi][ni][r] + bv;
        }
    }
}

// ---------------------------------------------------------------------------
// Neighborhood attention, LDS-staged (unchanged from R2/R3).
// ---------------------------------------------------------------------------
__global__ __launch_bounds__(192) void na2d_kernel(
    const float* __restrict__ qkv, float* __restrict__ out)
{
    __shared__ float4 smem[32 * 97];   // 49.7 KB: f=0..15 k (h0,h1), 16..31 v

    int bp = blockIdx.x;
    const int g = bp % 3; bp /= 3;
    const int b = bp / 48;
    const int p = bp % 48;
    const int i0 = 2 * p, i1 = i0 + 1;
    const int K = 7 + 2 * g;
    const int c = K >> 1;

    const int tid = threadIdx.x;
    const int j = tid % 96;
    const int h = tid / 96;
    const int h8 = h * 8;

    int si0 = i0 - c; if (si0 < 0) si0 = 0; if (si0 > H_ - K) si0 = H_ - K;
    int si1 = i1 - c; if (si1 < 0) si1 = 0; if (si1 > H_ - K) si1 = H_ - K;
    const int d01 = si1 - si0;
    const int nr = d01 + K;

    int sj = j - c; if (sj < 0) sj = 0; if (sj > W_ - K) sj = W_ - K;

    const float* q0p = qkv + (size_t)((b * H_ + i0) * W_ + j) * QKVC + g * 192 + h * 32;
    const float* q1p = q0p + (size_t)W_ * QKVC;
    float4 q0[8], q1[8], y0[8], y1[8];
    #pragma unroll
    for (int d4 = 0; d4 < 8; ++d4) {
        float4 t0 = ((const float4*)q0p)[d4];
        float4 t1 = ((const float4*)q1p)[d4];
        t0.x *= SCALE; t0.y *= SCALE; t0.z *= SCALE; t0.w *= SCALE;
        t1.x *= SCALE; t1.y *= SCALE; t1.z *= SCALE; t1.w *= SCALE;
        q0[d4] = t0; q1[d4] = t1;
        y0[d4] = make_float4(0.f, 0.f, 0.f, 0.f);
        y1[d4] = make_float4(0.f, 0.f, 0.f, 0.f);
    }
    float l0 = 0.f, l1 = 0.f;

    const float4* qkv4 = (const float4*)qkv;

    for (int t = 0; t < nr; ++t) {
        const int r = si0 + t;
        __syncthreads();
        const size_t rowbase = (size_t)(b * H_ + r) * W_ * 144;
        #pragma unroll
        for (int it = 0; it < 16; ++it) {
            int idx = it * 192 + tid;
            int pix = idx >> 5;
            int f = idx & 31;
            smem[f * 97 + pix] = qkv4[rowbase + (size_t)pix * 144 + g * 48 + 16 + f];
        }
        __syncthreads();

        const bool a0 = (t < K);
        const bool a1 = (t >= d01);
        for (int wj = 0; wj < K; ++wj) {
            const int col = sj + wj;
            float dot0 = 0.f, dot1 = 0.f;
            #pragma unroll
            for (int d4 = 0; d4 < 8; ++d4) {
                float4 kk = smem[(h8 + d4) * 97 + col];
                float4 a = q0[d4], bq = q1[d4];
                dot0 += a.x * kk.x + a.y * kk.y + a.z * kk.z + a.w * kk.w;
                dot1 += bq.x * kk.x + bq.y * kk.y + bq.z * kk.z + bq.w * kk.w;
            }
            const float e0 = a0 ? __expf(dot0) : 0.f;
            const float e1 = a1 ? __expf(dot1) : 0.f;
            l0 += e0; l1 += e1;
            #pragma unroll
            for (int d4 = 0; d4 < 8; ++d4) {
                float4 vv = smem[(16 + h8 + d4) * 97 + col];
                y0[d4].x += e0 * vv.x; y0[d4].y += e0 * vv.y;
                y0[d4].z += e0 * vv.z; y0[d4].w += e0 * vv.w;
                y1[d4].x += e1 * vv.x; y1[d4].y += e1 * vv.y;
                y1[d4].z += e1 * vv.z; y1[d4].w += e1 * vv.w;
            }
        }
    }

    const float inv0 = 1.f / l0, inv1 = 1.f / l1;
    float* o0 = out + (size_t)((b * H_ + i0) * W_ + j) * C_ + g * 64 + h * 32;
    float* o1 = o0 + (size_t)W_ * C_;
    #pragma unroll
    for (int d4 = 0; d4 < 8; ++d4) {
        float4 w0, w1;
        w0.x = y0[d4].x * inv0; w0.y = y0[d4].y * inv0;
        w0.z = y0[d4].z * inv0; w0.w = y0[d4].w * inv0;
        w1.x = y1[d4].x * inv1; w1.y = y1[d4].y * inv1;
        w1.z = y1[d4].z * inv1; w1.w = y1[d4].w * inv1;
        ((float4*)o0)[d4] = w0;
        ((float4*)o1)[d4] = w1;
    }
}

// ---------------------------------------------------------------------------
extern "C" void kernel_launch(void* const* d_in, const int* in_sizes, int n_in,
                              void* d_out, int out_size, void* d_ws, size_t ws_size,
                              hipStream_t stream)
{
    const float* x      = (const float*)d_in[0];
    const float* w_qkv  = (const float*)d_in[1];
    const float* b_qkv  = (const float*)d_in[2];
    const float* w_proj = (const float*)d_in[3];
    const float* b_proj = (const float*)d_in[4];
    float* out = (float*)d_out;

    // Workspace layout (xh aliases the attn region; xh dead after GEMM1):
    //   [qkv fp32 84.93MB][region 28.31MB: xh bf16 then attn fp32][wqt][wpt_h][wpt_l]
    char* ws = (char*)d_ws;
    float*    qkv   = (float*)ws;
    char*     reg1  = ws + (size_t)NPIX * QKVC * 4;
    ushort_t* xh    = (ushort_t*)reg1;
    float*    attn  = (float*)reg1;
    char*     wbase = reg1 + (size_t)NPIX * C_ * 4;
    ushort_t* wqt   = (ushort_t*)wbase;                        // 576x192 bf16
    ushort_t* wpt_h = (ushort_t*)(wbase + 576 * 192 * 2);      // 192x192 bf16
    ushort_t* wpt_l = (ushort_t*)(wbase + 576 * 192 * 2 + 192 * 192 * 2);

    // 0) conversions
    convert_x_kernel<<<(NPIX * C_ / 4 + 255) / 256, 256, 0, stream>>>(
        x, xh, NPIX * C_ / 4);
    convert_w_kernel<<<(576 * 192 + 192 * 192 + 255) / 256, 256, 0, stream>>>(
        w_qkv, w_proj, wqt, wpt_h, wpt_l);

    // 1) qkv = x @ w_qkv + b_qkv   (bf16 MFMA, 64x192 tiles)
    gemm_mfma2_kernel<false><<<(NPIX / 64) * (QKVC / 192), 256, 0, stream>>>(
        xh, wqt, nullptr, b_qkv, qkv, NPIX, QKVC, C_);

    // 2) neighborhood attention: 3 groups x 4 batches x 48 row-pairs
    na2d_kernel<<<576, 192, 0, stream>>>(qkv, attn);

    // 3) out = attn @ w_proj + b_proj  (split-bf16 x3 MFMA)
    gemm_mfma2_kernel<true><<<(NPIX / 64) * (C_ / 192), 256, 0, stream>>>(
        attn, wpt_h, wpt_l, b_proj, out, NPIX, C_, C_);
}